// Round 3
// baseline (3038.506 us; speedup 1.0000x reference)
//
#include <hip/hip_runtime.h>

#define TT 1024
#define BB 64
#define FF 256
#define HH 512

// ---------------------------------------------------------------------------
// Kernel 1: i_n = x @ W_ih^T + b_ih   ->  written into io (= d_out), later
// overwritten in-place by the recurrence with h_t.
// M = T*B = 65536, N = H = 512, K = F = 256. Tiles: 32(M) x 64(N) x 64(K).
// ---------------------------------------------------------------------------
__global__ __launch_bounds__(256) void in_gemm(
    const float* __restrict__ x, const float* __restrict__ Wih,
    const float* __restrict__ bih, float* __restrict__ io)
{
    __shared__ float xs[32][68];   // pad 68: conflict-free + 16B-aligned rows
    __shared__ float wst[64][68];  // transposed W tile: wst[k][j]

    const int bid = blockIdx.x;
    const int rb = bid >> 3, cb = bid & 7;
    const int m0 = rb * 32, n0 = cb * 64;
    const int t  = threadIdx.x;
    const int ti = t >> 4, tj = t & 15;

    float acc[2][4] = {{0.f,0.f,0.f,0.f},{0.f,0.f,0.f,0.f}};

    for (int k0 = 0; k0 < FF; k0 += 64) {
        {   // x tile: 32x64 floats, 8 per thread
            int flat = t * 8;
            int row = flat >> 6, col = flat & 63;
            const float* src = &x[(size_t)(m0 + row) * FF + k0 + col];
            float4 a = *(const float4*)&src[0];
            float4 b = *(const float4*)&src[4];
            *(float4*)&xs[row][col]     = a;
            *(float4*)&xs[row][col + 4] = b;
        }
        {   // W tile transposed: 64x64 floats, 16 per thread
            int j  = t >> 2;          // 0..63
            int kk = (t & 3) * 16;    // 0,16,32,48
            const float* src = &Wih[(size_t)(n0 + j) * FF + k0 + kk];
            #pragma unroll
            for (int q = 0; q < 4; ++q) {
                float4 v = *(const float4*)&src[q * 4];
                wst[kk + q*4 + 0][j] = v.x;
                wst[kk + q*4 + 1][j] = v.y;
                wst[kk + q*4 + 2][j] = v.z;
                wst[kk + q*4 + 3][j] = v.w;
            }
        }
        __syncthreads();
        #pragma unroll
        for (int k = 0; k < 64; k += 4) {
            float4 xa = *(const float4*)&xs[ti][k];
            float4 xb = *(const float4*)&xs[ti + 16][k];
            #pragma unroll
            for (int q = 0; q < 4; ++q) {
                float4 wv = *(const float4*)&wst[k + q][tj * 4];
                float xav = (&xa.x)[q], xbv = (&xb.x)[q];
                acc[0][0] = fmaf(xav, wv.x, acc[0][0]);
                acc[0][1] = fmaf(xav, wv.y, acc[0][1]);
                acc[0][2] = fmaf(xav, wv.z, acc[0][2]);
                acc[0][3] = fmaf(xav, wv.w, acc[0][3]);
                acc[1][0] = fmaf(xbv, wv.x, acc[1][0]);
                acc[1][1] = fmaf(xbv, wv.y, acc[1][1]);
                acc[1][2] = fmaf(xbv, wv.z, acc[1][2]);
                acc[1][3] = fmaf(xbv, wv.w, acc[1][3]);
            }
        }
        __syncthreads();
    }

    float4 bv = *(const float4*)&bih[n0 + tj * 4];
    float4 r0 = make_float4(acc[0][0]+bv.x, acc[0][1]+bv.y, acc[0][2]+bv.z, acc[0][3]+bv.w);
    float4 r1 = make_float4(acc[1][0]+bv.x, acc[1][1]+bv.y, acc[1][2]+bv.z, acc[1][3]+bv.w);
    *(float4*)&io[(size_t)(m0 + ti)      * HH + n0 + tj * 4] = r0;
    *(float4*)&io[(size_t)(m0 + ti + 16) * HH + n0 + tj * 4] = r1;
}

// ---------------------------------------------------------------------------
// Kernel 2: persistent recurrence. 256 WGs = 8 row-slices (s) x 32 batch-
// groups (g, 2 batches each); W_hh slice persistent in registers.
//
// ROUND-3 CHANGE: W registers are PINNED via empty asm "+v" after the load.
// Rounds 1-2 had VGPR_Count=48: with __restrict__ Whh the compiler proved
// the W loads rematerializable and re-loaded 256 KB/WG from L2 every step
// (~4700 cy/step ~= 2.0 ms total -- the round-2 bottleneck). The asm makes
// the values non-rederivable, forcing true residency (~64 VGPRs of W;
// peak pressure ~95 < 128 cap at launch_bounds(1024,4)).
// Sync protocol (round 2, keep): relaxed agent atomics only -- no fences,
// no L2 writeback/invalidate; __syncthreads() vmcnt-drain carries ordering.
// ---------------------------------------------------------------------------
__global__ __launch_bounds__(1024, 4) void mgu_rec(
    const float* __restrict__ Whh, const float* __restrict__ bhh,
    float* __restrict__ io, float* __restrict__ hbuf,
    unsigned int* __restrict__ bar)
{
    const int bid = blockIdx.x;
    const int s   = bid >> 5;     // row slice 0..7
    const int g   = bid & 31;     // batch group 0..31
    const int c0  = g * 2;        // first batch of this group
    const int tid = threadIdx.x;
    const int w   = tid >> 6;     // wave 0..15 -> k-slice
    const int l   = tid & 63;     // lane -> row offset within slice

    __shared__ float hst[2][HH];      // staged h for the 2 batches (4 KB)
    __shared__ float red[16][4][64];  // per-wave partials (16 KB)

    // --- load persistent W registers (64 floats/thread), then PIN them ---
    float Wf[32], Wn[32];
    {
        const float* pf = &Whh[(size_t)(s * 64 + l) * HH + w * 32];
        const float* pn = &Whh[(size_t)(512 + s * 64 + l) * HH + w * 32];
        #pragma unroll
        for (int q = 0; q < 8; ++q) {
            float4 a = *(const float4*)&pf[q * 4];
            Wf[q*4+0] = a.x; Wf[q*4+1] = a.y; Wf[q*4+2] = a.z; Wf[q*4+3] = a.w;
            float4 b = *(const float4*)&pn[q * 4];
            Wn[q*4+0] = b.x; Wn[q*4+1] = b.y; Wn[q*4+2] = b.z; Wn[q*4+3] = b.w;
        }
        // pin: values become non-rederivable -> regalloc cannot re-load
        // from memory inside the step loop; must keep in VGPRs.
        #pragma unroll
        for (int q = 0; q < 32; ++q) {
            asm volatile("" : "+v"(Wf[q]), "+v"(Wn[q]));
        }
    }

    float bfv = 0.f, bnv = 0.f;
    if (tid < 128) {
        int ej = tid & 63;
        bfv = bhh[s * 64 + ej];
        bnv = bhh[512 + s * 64 + ej];
    }

    unsigned int* mybar = &bar[g * 32];  // 128B-spaced line per group

    for (int t = 0; t < TT; ++t) {
        const int p = t & 1;

        // stage h (2 batches x 512) into LDS via relaxed agent loads (sc1:
        // reads the coherence point, no stale-L2 hazard, no cache maint.)
        {
            int c = tid >> 9;       // 0..1
            int k = tid & 511;
            const float* src = &hbuf[p * BB * HH + (c0 + c) * HH + k];
            hst[c][k] = __hip_atomic_load(src, __ATOMIC_RELAXED,
                                          __HIP_MEMORY_SCOPE_AGENT);
        }

        // early i_n load for epilogue threads (independent of h)
        float in_v = 0.f;
        size_t oidx = 0;
        if (tid < 128) {
            int ec = tid >> 6, ej = tid & 63;
            oidx = ((size_t)t * BB + (c0 + ec)) * HH + s * 64 + ej;
            in_v = io[oidx];
        }
        __syncthreads();

        // partial dot products: 128 FMA/thread, h via LDS broadcast.
        // sched_barrier(0) per chunk caps live h-vectors at 2 so total
        // pressure stays under the 128-VGPR cap (W must not spill).
        float pf0 = 0.f, pf1 = 0.f, pn0 = 0.f, pn1 = 0.f;
        #pragma unroll
        for (int q = 0; q < 8; ++q) {
            float4 h0 = *(const float4*)&hst[0][w * 32 + q * 4];
            float4 h1 = *(const float4*)&hst[1][w * 32 + q * 4];
            pf0 = fmaf(Wf[q*4+0], h0.x, pf0); pn0 = fmaf(Wn[q*4+0], h0.x, pn0);
            pf1 = fmaf(Wf[q*4+0], h1.x, pf1); pn1 = fmaf(Wn[q*4+0], h1.x, pn1);
            pf0 = fmaf(Wf[q*4+1], h0.y, pf0); pn0 = fmaf(Wn[q*4+1], h0.y, pn0);
            pf1 = fmaf(Wf[q*4+1], h1.y, pf1); pn1 = fmaf(Wn[q*4+1], h1.y, pn1);
            pf0 = fmaf(Wf[q*4+2], h0.z, pf0); pn0 = fmaf(Wn[q*4+2], h0.z, pn0);
            pf1 = fmaf(Wf[q*4+2], h1.z, pf1); pn1 = fmaf(Wn[q*4+2], h1.z, pn1);
            pf0 = fmaf(Wf[q*4+3], h0.w, pf0); pn0 = fmaf(Wn[q*4+3], h0.w, pn0);
            pf1 = fmaf(Wf[q*4+3], h1.w, pf1); pn1 = fmaf(Wn[q*4+3], h1.w, pn1);
            __builtin_amdgcn_sched_barrier(0);
        }
        red[w][0][l] = pf0; red[w][1][l] = pf1;
        red[w][2][l] = pn0; red[w][3][l] = pn1;
        __syncthreads();

        // epilogue: 128 threads -> (batch ec, row ej)
        if (tid < 128) {
            int ec = tid >> 6, ej = tid & 63;
            float fs = 0.f, ns = 0.f;
            #pragma unroll
            for (int ww = 0; ww < 16; ++ww) {
                fs += red[ww][ec][ej];
                ns += red[ww][2 + ec][ej];
            }
            float fg    = 1.f / (1.f + expf(-(fs + bfv)));
            float nval  = tanhf(in_v + fg * (ns + bnv));
            float hprev = hst[ec][s * 64 + ej];
            float hnew  = nval + (1.f - fg) * (hprev - nval);
            io[oidx] = hnew;  // normal store (read only by harness)
            // h for next step: relaxed agent store -> at L3 once this
            // wave's vmcnt drains (at the next __syncthreads)
            float* dst = &hbuf[(p ^ 1) * BB * HH + (c0 + ec) * HH + s * 64 + ej];
            __hip_atomic_store(dst, hnew, __ATOMIC_RELAXED,
                               __HIP_MEMORY_SCOPE_AGENT);
        }
        __syncthreads();  // all waves drain vmcnt(0) -> h stores at L3

        // 8-WG monotonic barrier: relaxed agent RMW + relaxed spin.
        if (tid == 0) {
            __hip_atomic_fetch_add(mybar, 1u, __ATOMIC_RELAXED,
                                   __HIP_MEMORY_SCOPE_AGENT);
            unsigned int target = 8u * (unsigned int)(t + 1);
            while (__hip_atomic_load(mybar, __ATOMIC_RELAXED,
                                     __HIP_MEMORY_SCOPE_AGENT) < target) {
                __builtin_amdgcn_s_sleep(1);
            }
        }
        __syncthreads();
    }
}

// ---------------------------------------------------------------------------
extern "C" void kernel_launch(void* const* d_in, const int* in_sizes, int n_in,
                              void* d_out, int out_size, void* d_ws, size_t ws_size,
                              hipStream_t stream)
{
    const float* x   = (const float*)d_in[0];
    const float* Wih = (const float*)d_in[1];
    const float* Whh = (const float*)d_in[2];
    const float* bih = (const float*)d_in[3];
    const float* bhh = (const float*)d_in[4];
    float* io = (float*)d_out;

    float*        hbuf = (float*)d_ws;                                   // 2*64*512 f32 = 256 KB
    unsigned int* bar  = (unsigned int*)((char*)d_ws + 2 * BB * HH * 4); // 32 x 128B lines

    // zero ping-pong h buffer (h0 = 0) and barrier counters; re-runs every
    // launch/replay -> deterministic.
    hipMemsetAsync(d_ws, 0, 2 * BB * HH * 4 + 32 * 128, stream);

    in_gemm<<<dim3(16384), dim3(256), 0, stream>>>(x, Wih, bih, io);
    mgu_rec<<<dim3(256), dim3(1024), 0, stream>>>(Whh, bhh, io, hbuf, bar);
}

// Round 4
// 2734.803 us; speedup vs baseline: 1.1111x; 1.1111x over previous
//
#include <hip/hip_runtime.h>

#define TT 1024
#define BB 64
#define FF 256
#define HH 512

// ---------------------------------------------------------------------------
// Kernel 1: i_n = x @ W_ih^T + b_ih   ->  written into io (= d_out), later
// overwritten in-place by the recurrence with h_t.
// M = T*B = 65536, N = H = 512, K = F = 256. Tiles: 32(M) x 64(N) x 64(K).
// ---------------------------------------------------------------------------
__global__ __launch_bounds__(256) void in_gemm(
    const float* __restrict__ x, const float* __restrict__ Wih,
    const float* __restrict__ bih, float* __restrict__ io)
{
    __shared__ float xs[32][68];   // pad 68: conflict-free + 16B-aligned rows
    __shared__ float wst[64][68];  // transposed W tile: wst[k][j]

    const int bid = blockIdx.x;
    const int rb = bid >> 3, cb = bid & 7;
    const int m0 = rb * 32, n0 = cb * 64;
    const int t  = threadIdx.x;
    const int ti = t >> 4, tj = t & 15;

    float acc[2][4] = {{0.f,0.f,0.f,0.f},{0.f,0.f,0.f,0.f}};

    for (int k0 = 0; k0 < FF; k0 += 64) {
        {   // x tile: 32x64 floats, 8 per thread
            int flat = t * 8;
            int row = flat >> 6, col = flat & 63;
            const float* src = &x[(size_t)(m0 + row) * FF + k0 + col];
            float4 a = *(const float4*)&src[0];
            float4 b = *(const float4*)&src[4];
            *(float4*)&xs[row][col]     = a;
            *(float4*)&xs[row][col + 4] = b;
        }
        {   // W tile transposed: 64x64 floats, 16 per thread
            int j  = t >> 2;          // 0..63
            int kk = (t & 3) * 16;    // 0,16,32,48
            const float* src = &Wih[(size_t)(n0 + j) * FF + k0 + kk];
            #pragma unroll
            for (int q = 0; q < 4; ++q) {
                float4 v = *(const float4*)&src[q * 4];
                wst[kk + q*4 + 0][j] = v.x;
                wst[kk + q*4 + 1][j] = v.y;
                wst[kk + q*4 + 2][j] = v.z;
                wst[kk + q*4 + 3][j] = v.w;
            }
        }
        __syncthreads();
        #pragma unroll
        for (int k = 0; k < 64; k += 4) {
            float4 xa = *(const float4*)&xs[ti][k];
            float4 xb = *(const float4*)&xs[ti + 16][k];
            #pragma unroll
            for (int q = 0; q < 4; ++q) {
                float4 wv = *(const float4*)&wst[k + q][tj * 4];
                float xav = (&xa.x)[q], xbv = (&xb.x)[q];
                acc[0][0] = fmaf(xav, wv.x, acc[0][0]);
                acc[0][1] = fmaf(xav, wv.y, acc[0][1]);
                acc[0][2] = fmaf(xav, wv.z, acc[0][2]);
                acc[0][3] = fmaf(xav, wv.w, acc[0][3]);
                acc[1][0] = fmaf(xbv, wv.x, acc[1][0]);
                acc[1][1] = fmaf(xbv, wv.y, acc[1][1]);
                acc[1][2] = fmaf(xbv, wv.z, acc[1][2]);
                acc[1][3] = fmaf(xbv, wv.w, acc[1][3]);
            }
        }
        __syncthreads();
    }

    float4 bv = *(const float4*)&bih[n0 + tj * 4];
    float4 r0 = make_float4(acc[0][0]+bv.x, acc[0][1]+bv.y, acc[0][2]+bv.z, acc[0][3]+bv.w);
    float4 r1 = make_float4(acc[1][0]+bv.x, acc[1][1]+bv.y, acc[1][2]+bv.z, acc[1][3]+bv.w);
    *(float4*)&io[(size_t)(m0 + ti)      * HH + n0 + tj * 4] = r0;
    *(float4*)&io[(size_t)(m0 + ti + 16) * HH + n0 + tj * 4] = r1;
}

// ---------------------------------------------------------------------------
// Kernel 2: persistent recurrence. 256 WGs = 8 row-slices (s) x 32 batch-
// groups (g, 2 batches each); W_hh slice persistent in registers.
//
// ROUND-4 CHANGE: the W pin is now ONE asm statement with 64 CONSTANT-INDEX
// operands. Round 3's pin was a loop (runtime index into Wf[q] as an asm
// operand) -> arrays became addressable -> SROA demoted Wf/Wn to SCRATCH,
// and the step loop re-read 256 KB/WG/step from scratch (same L2 traffic as
// round 2's remat; identical counters proved it). Constant indices let SROA
// promote to 64 SSA scalars; the asm makes them non-rematerializable; with
// pressure ~95 < 128-VGPR cap (16-wave WG => <=128/wave) they stay resident.
// Sync protocol (round 2, keep): relaxed agent atomics only, no fences.
// ---------------------------------------------------------------------------
#define P4(A,i) "+v"(A[(i)+0]), "+v"(A[(i)+1]), "+v"(A[(i)+2]), "+v"(A[(i)+3])

__global__ __launch_bounds__(1024, 4) void mgu_rec(
    const float* __restrict__ Whh, const float* __restrict__ bhh,
    float* __restrict__ io, float* __restrict__ hbuf,
    unsigned int* __restrict__ bar)
{
    const int bid = blockIdx.x;
    const int s   = bid >> 5;     // row slice 0..7
    const int g   = bid & 31;     // batch group 0..31
    const int c0  = g * 2;        // first batch of this group
    const int tid = threadIdx.x;
    const int w   = tid >> 6;     // wave 0..15 -> k-slice
    const int l   = tid & 63;     // lane -> row offset within slice

    __shared__ float hst[2][HH];      // staged h for the 2 batches (4 KB)
    __shared__ float red[16][4][64];  // per-wave partials (16 KB)

    // --- load persistent W registers (64 floats/thread), then PIN them ---
    float Wf[32], Wn[32];
    {
        const float* pf = &Whh[(size_t)(s * 64 + l) * HH + w * 32];
        const float* pn = &Whh[(size_t)(512 + s * 64 + l) * HH + w * 32];
        #pragma unroll
        for (int q = 0; q < 8; ++q) {
            float4 a = *(const float4*)&pf[q * 4];
            Wf[q*4+0] = a.x; Wf[q*4+1] = a.y; Wf[q*4+2] = a.z; Wf[q*4+3] = a.w;
            float4 b = *(const float4*)&pn[q * 4];
            Wn[q*4+0] = b.x; Wn[q*4+1] = b.y; Wn[q*4+2] = b.z; Wn[q*4+3] = b.w;
        }
    }
    // single pin, all 64 values, constant indices only
    asm volatile("" :
        P4(Wf,0), P4(Wf,4), P4(Wf,8),  P4(Wf,12),
        P4(Wf,16), P4(Wf,20), P4(Wf,24), P4(Wf,28),
        P4(Wn,0), P4(Wn,4), P4(Wn,8),  P4(Wn,12),
        P4(Wn,16), P4(Wn,20), P4(Wn,24), P4(Wn,28));

    float bfv = 0.f, bnv = 0.f;
    if (tid < 128) {
        int ej = tid & 63;
        bfv = bhh[s * 64 + ej];
        bnv = bhh[512 + s * 64 + ej];
    }

    unsigned int* mybar = &bar[g * 32];  // 128B-spaced line per group

    for (int t = 0; t < TT; ++t) {
        const int p = t & 1;

        // stage h (2 batches x 512) into LDS via relaxed agent loads (sc1:
        // reads the coherence point, no stale-L2 hazard, no cache maint.)
        {
            int c = tid >> 9;       // 0..1
            int k = tid & 511;
            const float* src = &hbuf[p * BB * HH + (c0 + c) * HH + k];
            hst[c][k] = __hip_atomic_load(src, __ATOMIC_RELAXED,
                                          __HIP_MEMORY_SCOPE_AGENT);
        }

        // early i_n load for epilogue threads (independent of h)
        float in_v = 0.f;
        size_t oidx = 0;
        if (tid < 128) {
            int ec = tid >> 6, ej = tid & 63;
            oidx = ((size_t)t * BB + (c0 + ec)) * HH + s * 64 + ej;
            in_v = io[oidx];
        }
        __syncthreads();

        // partial dot products: 128 FMA/thread, h via LDS broadcast.
        // sched_barrier(0) per chunk caps live h-vectors at 2 so total
        // pressure stays under the 128-VGPR cap (W must not spill).
        float pf0 = 0.f, pf1 = 0.f, pn0 = 0.f, pn1 = 0.f;
        #pragma unroll
        for (int q = 0; q < 8; ++q) {
            float4 h0 = *(const float4*)&hst[0][w * 32 + q * 4];
            float4 h1 = *(const float4*)&hst[1][w * 32 + q * 4];
            pf0 = fmaf(Wf[q*4+0], h0.x, pf0); pn0 = fmaf(Wn[q*4+0], h0.x, pn0);
            pf1 = fmaf(Wf[q*4+0], h1.x, pf1); pn1 = fmaf(Wn[q*4+0], h1.x, pn1);
            pf0 = fmaf(Wf[q*4+1], h0.y, pf0); pn0 = fmaf(Wn[q*4+1], h0.y, pn0);
            pf1 = fmaf(Wf[q*4+1], h1.y, pf1); pn1 = fmaf(Wn[q*4+1], h1.y, pn1);
            pf0 = fmaf(Wf[q*4+2], h0.z, pf0); pn0 = fmaf(Wn[q*4+2], h0.z, pn0);
            pf1 = fmaf(Wf[q*4+2], h1.z, pf1); pn1 = fmaf(Wn[q*4+2], h1.z, pn1);
            pf0 = fmaf(Wf[q*4+3], h0.w, pf0); pn0 = fmaf(Wn[q*4+3], h0.w, pn0);
            pf1 = fmaf(Wf[q*4+3], h1.w, pf1); pn1 = fmaf(Wn[q*4+3], h1.w, pn1);
            __builtin_amdgcn_sched_barrier(0);
        }
        red[w][0][l] = pf0; red[w][1][l] = pf1;
        red[w][2][l] = pn0; red[w][3][l] = pn1;
        __syncthreads();

        // epilogue: 128 threads -> (batch ec, row ej)
        if (tid < 128) {
            int ec = tid >> 6, ej = tid & 63;
            float fs = 0.f, ns = 0.f;
            #pragma unroll
            for (int ww = 0; ww < 16; ++ww) {
                fs += red[ww][ec][ej];
                ns += red[ww][2 + ec][ej];
            }
            float fg    = 1.f / (1.f + expf(-(fs + bfv)));
            float nval  = tanhf(in_v + fg * (ns + bnv));
            float hprev = hst[ec][s * 64 + ej];
            float hnew  = nval + (1.f - fg) * (hprev - nval);
            io[oidx] = hnew;  // normal store (read only by harness)
            // h for next step: relaxed agent store -> at L3 once this
            // wave's vmcnt drains (at the next __syncthreads)
            float* dst = &hbuf[(p ^ 1) * BB * HH + (c0 + ec) * HH + s * 64 + ej];
            __hip_atomic_store(dst, hnew, __ATOMIC_RELAXED,
                               __HIP_MEMORY_SCOPE_AGENT);
        }
        __syncthreads();  // all waves drain vmcnt(0) -> h stores at L3

        // 8-WG monotonic barrier: relaxed agent RMW + relaxed spin.
        if (tid == 0) {
            __hip_atomic_fetch_add(mybar, 1u, __ATOMIC_RELAXED,
                                   __HIP_MEMORY_SCOPE_AGENT);
            unsigned int target = 8u * (unsigned int)(t + 1);
            while (__hip_atomic_load(mybar, __ATOMIC_RELAXED,
                                     __HIP_MEMORY_SCOPE_AGENT) < target) {
                __builtin_amdgcn_s_sleep(1);
            }
        }
        __syncthreads();
    }
}

// ---------------------------------------------------------------------------
extern "C" void kernel_launch(void* const* d_in, const int* in_sizes, int n_in,
                              void* d_out, int out_size, void* d_ws, size_t ws_size,
                              hipStream_t stream)
{
    const float* x   = (const float*)d_in[0];
    const float* Wih = (const float*)d_in[1];
    const float* Whh = (const float*)d_in[2];
    const float* bih = (const float*)d_in[3];
    const float* bhh = (const float*)d_in[4];
    float* io = (float*)d_out;

    float*        hbuf = (float*)d_ws;                                   // 2*64*512 f32 = 256 KB
    unsigned int* bar  = (unsigned int*)((char*)d_ws + 2 * BB * HH * 4); // 32 x 128B lines

    // zero ping-pong h buffer (h0 = 0) and barrier counters; re-runs every
    // launch/replay -> deterministic.
    hipMemsetAsync(d_ws, 0, 2 * BB * HH * 4 + 32 * 128, stream);

    in_gemm<<<dim3(16384), dim3(256), 0, stream>>>(x, Wih, bih, io);
    mgu_rec<<<dim3(256), dim3(1024), 0, stream>>>(Whh, bhh, io, hbuf, bar);
}